// Round 7
// baseline (78.063 us; speedup 1.0000x reference)
//
#include <hip/hip_runtime.h>
#include <math.h>

constexpr int BGR = 1024;
constexpr int NN  = 128;
constexpr int EG  = 2048;
constexpr int FIN = 30;
constexpr int H1  = 30;
constexpr int H2  = 50;
constexpr int K1  = 103;
constexpr int K2  = 83;
constexpr int FCW = 100;
constexpr int NT  = 512;
constexpr int EPT = EG/NT;   // 4 packed edges/thread

// XB: node rows of 32 floats, chunk-rotated swizzle:
//   feature i of row s -> dword s*32 + (((i>>2)+s)&7)*4 + (i&3)
// XB is time-shared (barrier-separated): x -> W1quad -> h1g -> W2quad -> pool scratch
constexpr int XBSZ = NN*32;      // 16384 B
constexpr int PMX = 0, PSM = 400, POL = 800, ZFC = 900;   // pool scratch dword offsets

__device__ __forceinline__ void row_fma(int s, float w, const float* XB, int cq,
                                        float4& ac0, float4& ac1, float4& ac2, float4& ac3)
{
  int base=s<<5, rot=s&7;
  float4 v0=*(const float4*)&XB[base+(((cq  +rot)&7)<<2)];
  float4 v1=*(const float4*)&XB[base+(((cq+1+rot)&7)<<2)];
  float4 v2=*(const float4*)&XB[base+(((cq+2+rot)&7)<<2)];
  float4 v3=*(const float4*)&XB[base+(((cq+3+rot)&7)<<2)];
  ac0.x=fmaf(w,v0.x,ac0.x); ac0.y=fmaf(w,v0.y,ac0.y); ac0.z=fmaf(w,v0.z,ac0.z); ac0.w=fmaf(w,v0.w,ac0.w);
  ac1.x=fmaf(w,v1.x,ac1.x); ac1.y=fmaf(w,v1.y,ac1.y); ac1.z=fmaf(w,v1.z,ac1.z); ac1.w=fmaf(w,v1.w,ac1.w);
  ac2.x=fmaf(w,v2.x,ac2.x); ac2.y=fmaf(w,v2.y,ac2.y); ac2.z=fmaf(w,v2.z,ac2.z); ac2.w=fmaf(w,v2.w,ac2.w);
  ac3.x=fmaf(w,v3.x,ac3.x); ac3.y=fmaf(w,v3.y,ac3.y); ac3.z=fmaf(w,v3.z,ac3.z); ac3.w=fmaf(w,v3.w,ac3.w);
}

#define QRED(v) { v.x+=__shfl_xor(v.x,1,64); v.y+=__shfl_xor(v.y,1,64); \
                  v.z+=__shfl_xor(v.z,1,64); v.w+=__shfl_xor(v.w,1,64); }

__global__ __launch_bounds__(NT, 8) void gnn_fused(
    const float* __restrict__ x, const int* __restrict__ ei,
    const float* __restrict__ W1, const float* __restrict__ b1, const float* __restrict__ p1,
    const float* __restrict__ W2, const float* __restrict__ b2, const float* __restrict__ p2,
    const float* __restrict__ fc1W, const float* __restrict__ fc1b,
    const float* __restrict__ fc2W, const float* __restrict__ fc2b,
    float* __restrict__ out)
{
  const int g = blockIdx.x, tid = threadIdx.x;
  const int lane = tid&63;
  const int nA = tid>>2;            // node (0..127)
  const int hf = (tid>>1)&1;        // feature half
  const int epar = tid&1;           // edge parity
  const int qd = (hf<<1)|epar;      // quad class

  __shared__ float XB[XBSZ];
  __shared__ unsigned char eord[EG];
  __shared__ int   cur[NN];
  __shared__ short cstart[NN];
  __shared__ float dsc[NN];         // dinv <-> score (barrier-guarded)
  __shared__ signed char rmap[NN];
  __shared__ int sh_wtot;

  // ---- packed edges in registers: src | dst<<8 ----
  int epk[EPT];
  {
    const int* srcg = ei + (size_t)g*EG;
    const int* dstg = ei + (size_t)BGR*EG + (size_t)g*EG;
    #pragma unroll
    for (int j=0;j<EPT;j++){ int e=tid+j*NT; epk[j]=(srcg[e]&127)|((dstg[e]&127)<<8); }
  }
  // ---- stage x into swizzled XB ----
  for (int l2=tid; l2<NN*15; l2+=NT){
    int n=l2/15, i=(l2-n*15)*2;
    float2 v=*(const float2*)&x[(size_t)g*NN*FIN + n*FIN + i];
    *(float2*)&XB[(n<<5) + ((((i>>2)+n)&7)<<2) + (i&3)] = v;
  }
  if (tid<NN) cur[tid]=0;
  __syncthreads();

  // ================= CSR build 1 =================
  #pragma unroll
  for (int j=0;j<EPT;j++) atomicAdd(&cur[epk[j]>>8],1);
  __syncthreads();
  {
    int mydeg=(tid<NN)?cur[tid]:0;
    int v=mydeg;
    #pragma unroll
    for (int off=1;off<64;off<<=1){ int t=__shfl_up(v,off,64); if (lane>=off) v+=t; }
    if (tid==63) sh_wtot=v;
    __syncthreads();
    int start=v-mydeg+((tid>=64)?sh_wtot:0);
    if (tid<NN){ cur[tid]=start; cstart[tid]=(short)start; dsc[tid]=1.0f/sqrtf((float)mydeg+1.0f); }
  }
  __syncthreads();
  #pragma unroll
  for (int j=0;j<EPT;j++){ int p=atomicAdd(&cur[epk[j]>>8],1); eord[p]=(unsigned char)(epk[j]&255); }
  __syncthreads();

  // ================= gather1 -> regs (quad: half-features x edge-parity) =====
  float4 ac0={0,0,0,0},ac1={0,0,0,0},ac2={0,0,0,0},ac3={0,0,0,0};
  {
    const int cq=hf<<2;
    int e0=cstart[nA], e1=cur[nA];
    float di=dsc[nA];
    for (int k=e0+epar;k<e1;k+=2){
      int s=eord[k]; float w=di*dsc[s];
      row_fma(s,w,XB,cq,ac0,ac1,ac2,ac3);
    }
    QRED(ac0) QRED(ac1) QRED(ac2) QRED(ac3)                  // combine edge parities
    row_fma(nA, 1.0f/((float)(e1-e0)+1.0f), XB, cq, ac0,ac1,ac2,ac3);   // self loop
  }
  __syncthreads();                        // x dead

  // ---- stage W1 quad-split: region qd: [30][8], cols = hf*15+ep*8 .. +cnt ----
  for (int l=tid;l<960;l+=NT){
    int q=l/240, r=l-q*240, i=r>>3, c=r&7;
    int hq=q>>1, eq=q&1, cnt=eq?7:8;
    if (c<cnt) XB[q*240+i*8+c]=W1[i*H1+hq*15+eq*8+c];
  }
  __syncthreads();

  // ---- assemble full 30-feat aggregated row (other half via shfl_xor 2) ----
  float4 s0,s1,s2,s3;
  s0.x=__shfl_xor(ac0.x,2,64); s0.y=__shfl_xor(ac0.y,2,64); s0.z=__shfl_xor(ac0.z,2,64); s0.w=__shfl_xor(ac0.w,2,64);
  s1.x=__shfl_xor(ac1.x,2,64); s1.y=__shfl_xor(ac1.y,2,64); s1.z=__shfl_xor(ac1.z,2,64); s1.w=__shfl_xor(ac1.w,2,64);
  s2.x=__shfl_xor(ac2.x,2,64); s2.y=__shfl_xor(ac2.y,2,64); s2.z=__shfl_xor(ac2.z,2,64); s2.w=__shfl_xor(ac2.w,2,64);
  s3.x=__shfl_xor(ac3.x,2,64); s3.y=__shfl_xor(ac3.y,2,64); s3.z=__shfl_xor(ac3.z,2,64); s3.w=__shfl_xor(ac3.w,2,64);
  float4 A0=hf?s0:ac0, A1=hf?s1:ac1, A2=hf?s2:ac2, A3=hf?s3:ac3;
  float4 A4=hf?ac0:s0, A5=hf?ac1:s1, A6=hf?ac2:s2, A7=hf?ac3:s3;

  // ================= mm1 (i-major, quad outputs) =================
  const int cnt1 = epar?7:8;
  const int ob1  = hf*15+epar*8;
  float h[8];
  #pragma unroll
  for (int j=0;j<8;j++) h[j]=b1[ob1+((j<cnt1)?j:0)];
  {
    const float* wb=&XB[qd*240];
    #define M1S(i,ai) { const float4* wr=(const float4*)(wb+(i)*8); float4 w0=wr[0],w1=wr[1]; \
      h[0]=fmaf(ai,w0.x,h[0]); h[1]=fmaf(ai,w0.y,h[1]); h[2]=fmaf(ai,w0.z,h[2]); h[3]=fmaf(ai,w0.w,h[3]); \
      h[4]=fmaf(ai,w1.x,h[4]); h[5]=fmaf(ai,w1.y,h[5]); h[6]=fmaf(ai,w1.z,h[6]); h[7]=fmaf(ai,w1.w,h[7]); }
    M1S(0,A0.x) M1S(1,A0.y) M1S(2,A0.z) M1S(3,A0.w)
    M1S(4,A1.x) M1S(5,A1.y) M1S(6,A1.z) M1S(7,A1.w)
    M1S(8,A2.x) M1S(9,A2.y) M1S(10,A2.z) M1S(11,A2.w)
    M1S(12,A3.x) M1S(13,A3.y) M1S(14,A3.z) M1S(15,A3.w)
    M1S(16,A4.x) M1S(17,A4.y) M1S(18,A4.z) M1S(19,A4.w)
    M1S(20,A5.x) M1S(21,A5.y) M1S(22,A5.z) M1S(23,A5.w)
    M1S(24,A6.x) M1S(25,A6.y) M1S(26,A6.z) M1S(27,A6.w)
    M1S(28,A7.x) M1S(29,A7.y)
    #undef M1S
    #pragma unroll
    for (int j=0;j<8;j++) h[j]=fmaxf(h[j],0.f);
  }

  // ================= pool1: score (quad reduce), rank, gate+compact ==========
  {
    float nr=0.f;
    #pragma unroll
    for (int i=0;i<H1;i++){ float pv=p1[i]; nr+=pv*pv; }
    float d=0.f;
    #pragma unroll
    for (int j=0;j<8;j++) if (j<cnt1) d += h[j]*p1[ob1+j];
    d += __shfl_xor(d,1,64); d += __shfl_xor(d,2,64);
    float scv = tanhf(d/sqrtf(nr));
    if ((tid&3)==0) dsc[nA]=scv;
  }
  __syncthreads();
  {
    float si=dsc[nA];
    int m0=(tid&3)<<5, r=0;
    for (int m=m0;m<m0+32;m++){ float sm=dsc[m]; r += (sm>si)||(sm==si&&m<nA); }
    r += __shfl_xor(r,1,64); r += __shfl_xor(r,2,64);
    if ((tid&3)==0) rmap[nA]=(r<K1)?(signed char)r:(signed char)-1;
  }
  __syncthreads();
  {
    int r=rmap[nA];
    if (r>=0){
      float gv=dsc[nA];
      #pragma unroll
      for (int j=0;j<8;j++) if (j<cnt1){
        int i=ob1+j;
        XB[(r<<5)+((((i>>2)+r)&7)<<2)+(i&3)] = h[j]*gv;
      }
    }
  }
  #pragma unroll
  for (int j=0;j<EPT;j++){
    int ns=rmap[epk[j]&255], nd=rmap[epk[j]>>8];
    epk[j]=((ns|nd)<0)? -1 : (ns|(nd<<8));
  }
  if (tid<K1) cur[tid]=0;
  __syncthreads();

  // ================= CSR build 2 =================
  #pragma unroll
  for (int j=0;j<EPT;j++) if (epk[j]>=0) atomicAdd(&cur[epk[j]>>8],1);
  __syncthreads();
  {
    int mydeg=(tid<K1)?cur[tid]:0;
    int v=mydeg;
    #pragma unroll
    for (int off=1;off<64;off<<=1){ int t=__shfl_up(v,off,64); if (lane>=off) v+=t; }
    if (tid==63) sh_wtot=v;
    __syncthreads();
    int start=v-mydeg+((tid>=64)?sh_wtot:0);
    if (tid<K1){ cur[tid]=start; cstart[tid]=(short)start; dsc[tid]=1.0f/sqrtf((float)mydeg+1.0f); }
  }
  __syncthreads();
  #pragma unroll
  for (int j=0;j<EPT;j++) if (epk[j]>=0){ int p=atomicAdd(&cur[epk[j]>>8],1); eord[p]=(unsigned char)(epk[j]&255); }
  __syncthreads();

  // ================= gather2 -> regs =================
  ac0=(float4){0,0,0,0}; ac1=(float4){0,0,0,0}; ac2=(float4){0,0,0,0}; ac3=(float4){0,0,0,0};
  {
    const int cq=hf<<2;
    int e0=0,e1=0;
    if (nA<K1){ e0=cstart[nA]; e1=cur[nA]; }
    float di=(nA<K1)?dsc[nA]:0.f;
    for (int k=e0+epar;k<e1;k+=2){
      int s=eord[k]; float w=di*dsc[s];
      row_fma(s,w,XB,cq,ac0,ac1,ac2,ac3);
    }
    QRED(ac0) QRED(ac1) QRED(ac2) QRED(ac3)
    row_fma(nA, 1.0f/((float)(e1-e0)+1.0f), XB, cq, ac0,ac1,ac2,ac3);
  }
  __syncthreads();                        // h1g dead

  // ---- stage W2 quad-split: region qd: [30][16], cols = hf*25+ep*13 .. +cnt --
  for (int l=tid;l<1920;l+=NT){
    int q=l/480, r=l-q*480, i=r>>4, c=r&15;
    int hq=q>>1, eq=q&1, cnt=eq?12:13;
    if (c<cnt) XB[q*480+i*16+c]=W2[i*H2+hq*25+eq*13+c];
  }
  __syncthreads();

  // ---- assemble full 30-feat agg2 row ----
  s0.x=__shfl_xor(ac0.x,2,64); s0.y=__shfl_xor(ac0.y,2,64); s0.z=__shfl_xor(ac0.z,2,64); s0.w=__shfl_xor(ac0.w,2,64);
  s1.x=__shfl_xor(ac1.x,2,64); s1.y=__shfl_xor(ac1.y,2,64); s1.z=__shfl_xor(ac1.z,2,64); s1.w=__shfl_xor(ac1.w,2,64);
  s2.x=__shfl_xor(ac2.x,2,64); s2.y=__shfl_xor(ac2.y,2,64); s2.z=__shfl_xor(ac2.z,2,64); s2.w=__shfl_xor(ac2.w,2,64);
  s3.x=__shfl_xor(ac3.x,2,64); s3.y=__shfl_xor(ac3.y,2,64); s3.z=__shfl_xor(ac3.z,2,64); s3.w=__shfl_xor(ac3.w,2,64);
  A0=hf?s0:ac0; A1=hf?s1:ac1; A2=hf?s2:ac2; A3=hf?s3:ac3;
  A4=hf?ac0:s0; A5=hf?ac1:s1; A6=hf?ac2:s2; A7=hf?ac3:s3;

  // ================= mm2 (i-major, quad outputs) =================
  const int cnt2 = epar?12:13;
  const int ob2  = hf*25+epar*13;
  float oc[13];
  #pragma unroll
  for (int j=0;j<13;j++) oc[j]=b2[ob2+((j<cnt2)?j:0)];
  {
    const float* wb2=&XB[qd*480];
    #define M2S(i,ai) { const float4* wr=(const float4*)(wb2+(i)*16); float4 w0=wr[0],w1=wr[1],w2=wr[2]; float wl=wb2[(i)*16+12]; \
      oc[0]=fmaf(ai,w0.x,oc[0]); oc[1]=fmaf(ai,w0.y,oc[1]); oc[2]=fmaf(ai,w0.z,oc[2]); oc[3]=fmaf(ai,w0.w,oc[3]); \
      oc[4]=fmaf(ai,w1.x,oc[4]); oc[5]=fmaf(ai,w1.y,oc[5]); oc[6]=fmaf(ai,w1.z,oc[6]); oc[7]=fmaf(ai,w1.w,oc[7]); \
      oc[8]=fmaf(ai,w2.x,oc[8]); oc[9]=fmaf(ai,w2.y,oc[9]); oc[10]=fmaf(ai,w2.z,oc[10]); oc[11]=fmaf(ai,w2.w,oc[11]); \
      oc[12]=fmaf(ai,wl,oc[12]); }
    M2S(0,A0.x) M2S(1,A0.y) M2S(2,A0.z) M2S(3,A0.w)
    M2S(4,A1.x) M2S(5,A1.y) M2S(6,A1.z) M2S(7,A1.w)
    M2S(8,A2.x) M2S(9,A2.y) M2S(10,A2.z) M2S(11,A2.w)
    M2S(12,A3.x) M2S(13,A3.y) M2S(14,A3.z) M2S(15,A3.w)
    M2S(16,A4.x) M2S(17,A4.y) M2S(18,A4.z) M2S(19,A4.w)
    M2S(20,A5.x) M2S(21,A5.y) M2S(22,A5.z) M2S(23,A5.w)
    M2S(24,A6.x) M2S(25,A6.y) M2S(26,A6.z) M2S(27,A6.w)
    M2S(28,A7.x) M2S(29,A7.y)
    #undef M2S
    #pragma unroll
    for (int j=0;j<13;j++) oc[j]=fmaxf(oc[j],0.f);
  }

  // ================= pool2 score + rank =================
  {
    float nr=0.f;
    #pragma unroll
    for (int i=0;i<H2;i++){ float pv=p2[i]; nr+=pv*pv; }
    float d=0.f;
    #pragma unroll
    for (int j=0;j<13;j++) if (j<cnt2) d += oc[j]*p2[ob2+j];
    d += __shfl_xor(d,1,64); d += __shfl_xor(d,2,64);
    float scv = tanhf(d/sqrtf(nr));
    if (((tid&3)==0) && nA<K1) dsc[nA]=scv;
  }
  __syncthreads();
  {
    float si=(nA<K1)?dsc[nA]:0.f;
    int m0=(tid&3)*26, m1=m0+26; if (m1>K1) m1=K1;
    int r=0;
    for (int m=m0;m<m1;m++){ float sm=dsc[m]; r += (sm>si)||(sm==si&&m<nA); }
    r += __shfl_xor(r,1,64); r += __shfl_xor(r,2,64);
    if (((tid&3)==0) && nA<K1) rmap[nA]=(r<K2)?(signed char)1:(signed char)-1;
  }
  __syncthreads();

  // ================= gated global max/mean (register reduce over nodes) ======
  {
    bool kept = (nA<K1) && (rmap[nA]>0);
    float gv  = kept ? dsc[nA] : 0.f;
    float mx[13], sm[13];
    #pragma unroll
    for (int j=0;j<13;j++){ float v=oc[j]*gv; sm[j]=kept?v:0.f; mx[j]=kept?v:-3.4e38f; }
    #pragma unroll
    for (int off=4;off<64;off<<=1){
      #pragma unroll
      for (int j=0;j<13;j++){ mx[j]=fmaxf(mx[j],__shfl_xor(mx[j],off,64)); sm[j]+=__shfl_xor(sm[j],off,64); }
    }
    int wv=tid>>6;
    if ((tid&63)<4){     // lanes 0..3 hold the 4 quad feature groups
      #pragma unroll
      for (int j=0;j<13;j++) if (j<cnt2){
        XB[PMX + wv*50 + ob2 + j]=mx[j];
        XB[PSM + wv*50 + ob2 + j]=sm[j];
      }
    }
  }
  __syncthreads();
  if (tid<H2){
    float m=-3.4e38f, s=0.f;
    #pragma unroll
    for (int w=0;w<8;w++){ m=fmaxf(m,XB[PMX+w*50+tid]); s+=XB[PSM+w*50+tid]; }
    XB[POL+tid]=m;
    XB[POL+H2+tid]=s*(1.0f/(float)K2);
  }
  __syncthreads();

  // ================= fc1 + fc2 =================
  if (tid<FCW){
    float acc=fc1b[tid];
    #pragma unroll 4
    for (int i=0;i<2*H2;i++) acc += XB[POL+i]*fc1W[i*FCW+tid];
    XB[ZFC+tid]=fmaxf(acc,0.f);
  }
  __syncthreads();
  if (tid<64){
    float a=0.f;
    for (int j=tid;j<FCW;j+=64) a += XB[ZFC+j]*fc2W[j];
    #pragma unroll
    for (int off=32;off;off>>=1) a += __shfl_down(a,off,64);
    if (tid==0){
      float acc=fc2b[0]+a;
      out[g]=1.0f/(1.0f+expf(-acc));
    }
  }
}

extern "C" void kernel_launch(void* const* d_in, const int* in_sizes, int n_in,
                              void* d_out, int out_size, void* d_ws, size_t ws_size,
                              hipStream_t stream) {
  const float* x    = (const float*)d_in[0];
  const int*   ei   = (const int*)d_in[1];
  // d_in[2] = batch (unused; graphs are equal-size, contiguous)
  const float* W1   = (const float*)d_in[3];
  const float* b1   = (const float*)d_in[4];
  const float* p1   = (const float*)d_in[5];
  const float* W2   = (const float*)d_in[6];
  const float* b2   = (const float*)d_in[7];
  const float* p2   = (const float*)d_in[8];
  const float* fc1W = (const float*)d_in[9];
  const float* fc1b = (const float*)d_in[10];
  const float* fc2W = (const float*)d_in[11];
  const float* fc2b = (const float*)d_in[12];
  float* outp = (float*)d_out;

  gnn_fused<<<BGR, NT, 0, stream>>>(x, ei, W1, b1, p1, W2, b2, p2,
                                    fc1W, fc1b, fc2W, fc2b, outp);
}

// Round 8
// 61.728 us; speedup vs baseline: 1.2646x; 1.2646x over previous
//
#include <hip/hip_runtime.h>
#include <math.h>

constexpr int BGR = 1024;
constexpr int NN  = 128;
constexpr int EG  = 2048;
constexpr int FIN = 30;
constexpr int H1  = 30;
constexpr int H2  = 50;
constexpr int K1  = 103;
constexpr int K2  = 83;
constexpr int FCW = 100;
constexpr int NT  = 256;
constexpr int EPT = EG/NT;     // 8 packed edges/thread

// XB: node rows of 32 floats, chunk-rotated swizzle:
//   feature i of row s -> dword s*32 + (((i>>2)+s)&7)*4 + (i&3)
// AGG: aggregated rows, stride 36 floats (4 mod 32 banks -> consecutive rows spread).
constexpr int SA   = 36;
constexpr int XBSZ = NN*32;    // 16384 B
constexpr int AGSZ = NN*SA;    // 18432 B
constexpr int EGP  = EG + NN*4;   // padded CSR (deg rounded to x4)
// AGG tail scratch (rows >=104 free: dwords 3744..4607)
constexpr int SD0 = 3744;      // 256: per-half partial score dots
constexpr int PMX = 4000, PSM = 4100, POL = 4200, ZFC = 4300;

__device__ __forceinline__ void row_fma(int s, float w, const float* XB, int cq,
                                        float4& ac0, float4& ac1, float4& ac2, float4& ac3)
{
  int base=s<<5, rot=s&7;
  float4 v0=*(const float4*)&XB[base+(((cq  +rot)&7)<<2)];
  float4 v1=*(const float4*)&XB[base+(((cq+1+rot)&7)<<2)];
  float4 v2=*(const float4*)&XB[base+(((cq+2+rot)&7)<<2)];
  float4 v3=*(const float4*)&XB[base+(((cq+3+rot)&7)<<2)];
  ac0.x=fmaf(w,v0.x,ac0.x); ac0.y=fmaf(w,v0.y,ac0.y); ac0.z=fmaf(w,v0.z,ac0.z); ac0.w=fmaf(w,v0.w,ac0.w);
  ac1.x=fmaf(w,v1.x,ac1.x); ac1.y=fmaf(w,v1.y,ac1.y); ac1.z=fmaf(w,v1.z,ac1.z); ac1.w=fmaf(w,v1.w,ac1.w);
  ac2.x=fmaf(w,v2.x,ac2.x); ac2.y=fmaf(w,v2.y,ac2.y); ac2.z=fmaf(w,v2.z,ac2.z); ac2.w=fmaf(w,v2.w,ac2.w);
  ac3.x=fmaf(w,v3.x,ac3.x); ac3.y=fmaf(w,v3.y,ac3.y); ac3.z=fmaf(w,v3.z,ac3.z); ac3.w=fmaf(w,v3.w,ac3.w);
}

__global__ __launch_bounds__(NT, 4) void gnn_fused(
    const float* __restrict__ x, const int* __restrict__ ei,
    const float* __restrict__ W1, const float* __restrict__ b1, const float* __restrict__ p1,
    const float* __restrict__ W2, const float* __restrict__ b2, const float* __restrict__ p2,
    const float* __restrict__ fc1W, const float* __restrict__ fc1b,
    const float* __restrict__ fc2W, const float* __restrict__ fc2b,
    float* __restrict__ out)
{
  const int g = blockIdx.x, tid = threadIdx.x;
  const int lane = tid&63;
  const int wv   = tid>>6;                 // wave id 0..3
  const int hf   = wv&1;                   // wave-uniform feature half
  const int nG   = (tid>>7)*64 + lane;     // node: waves{0,1}->0..63, {2,3}->64..127
  const int hfu  = __builtin_amdgcn_readfirstlane(hf);   // force SGPR

  __shared__ float XB[XBSZ];
  __shared__ float AGG[AGSZ];
  __shared__ unsigned char eord[EGP];
  __shared__ int   cur[NN];
  __shared__ short cstart[NN];
  __shared__ float dsc[NN];
  __shared__ signed char rmap[NN];
  __shared__ int sh_wtot;

  // ---- packed edges in registers: src | dst<<8 ----
  int epk[EPT];
  {
    const int* srcg = ei + (size_t)g*EG;
    const int* dstg = ei + (size_t)BGR*EG + (size_t)g*EG;
    #pragma unroll
    for (int j=0;j<EPT;j++){ int e=tid+j*NT; epk[j]=(srcg[e]&127)|((dstg[e]&127)<<8); }
  }
  // ---- stage x into swizzled XB ----
  for (int l2=tid; l2<NN*15; l2+=NT){
    int n=l2/15, i=(l2-n*15)*2;
    float2 v=*(const float2*)&x[(size_t)g*NN*FIN + n*FIN + i];
    *(float2*)&XB[(n<<5) + ((((i>>2)+n)&7)<<2) + (i&3)] = v;
  }
  if (tid<NN) cur[tid]=0;
  __syncthreads();

  // ================= CSR build 1 =================
  #pragma unroll
  for (int j=0;j<EPT;j++) atomicAdd(&cur[epk[j]>>8],1);
  __syncthreads();
  {
    int mydeg=(tid<NN)?cur[tid]:0;
    int mydeg4=(mydeg+3)&~3;
    int v=mydeg4;
    #pragma unroll
    for (int off=1;off<64;off<<=1){ int t=__shfl_up(v,off,64); if (lane>=off) v+=t; }
    if (tid==63) sh_wtot=v;
    for (int l=tid;l<EGP/4;l+=NT) ((int*)eord)[l]=-1;     // holes = 0xFF
    __syncthreads();
    int start=v-mydeg4+((tid>=64)?sh_wtot:0);
    if (tid<NN){ cur[tid]=start; cstart[tid]=(short)start; dsc[tid]=1.0f/sqrtf((float)mydeg+1.0f); }
  }
  __syncthreads();
  #pragma unroll
  for (int j=0;j<EPT;j++){ int p=atomicAdd(&cur[epk[j]>>8],1); eord[p]=(unsigned char)(epk[j]&255); }
  __syncthreads();

  // ================= gather1: agg1 = A~ * x  (wave-mapped) ===================
  {
    float4 ac0={0,0,0,0},ac1={0,0,0,0},ac2={0,0,0,0},ac3={0,0,0,0};
    const int cq=hf<<2;
    int e0=cstart[nG], deg=cur[nG]-e0;
    float di=dsc[nG];
    int kend=e0+((deg+3)&~3);
    for (int k=e0;k<kend;k+=4){
      uchar4 ss=*(const uchar4*)&eord[k];
      float w0=(ss.x<128)? di*dsc[ss.x&127] : 0.f;
      float w1=(ss.y<128)? di*dsc[ss.y&127] : 0.f;
      float w2=(ss.z<128)? di*dsc[ss.z&127] : 0.f;
      float w3=(ss.w<128)? di*dsc[ss.w&127] : 0.f;
      row_fma(ss.x&127,w0,XB,cq,ac0,ac1,ac2,ac3);
      row_fma(ss.y&127,w1,XB,cq,ac0,ac1,ac2,ac3);
      row_fma(ss.z&127,w2,XB,cq,ac0,ac1,ac2,ac3);
      row_fma(ss.w&127,w3,XB,cq,ac0,ac1,ac2,ac3);
    }
    row_fma(nG, 1.0f/((float)deg+1.0f), XB, cq, ac0,ac1,ac2,ac3);   // self loop
    float* dp=&AGG[nG*SA + (hf<<4)];
    ((float4*)dp)[0]=ac0; ((float4*)dp)[1]=ac1; ((float4*)dp)[2]=ac2;
    if (!hf) ((float4*)dp)[3]=ac3;
    else     *(float2*)(dp+12)=make_float2(ac3.x,ac3.y);
  }
  __syncthreads();                 // x dead; agg1 ready

  // ================= mm1: scalar-W (wave-uniform) ============================
  float h[15];
  {
    float A[30];
    {
      const float* arow=&AGG[nG*SA];
      float4 t0=((const float4*)arow)[0],t1=((const float4*)arow)[1],t2=((const float4*)arow)[2],
             t3=((const float4*)arow)[3],t4=((const float4*)arow)[4],t5=((const float4*)arow)[5],
             t6=((const float4*)arow)[6];
      float2 t7=*(const float2*)(arow+28);
      A[0]=t0.x;A[1]=t0.y;A[2]=t0.z;A[3]=t0.w; A[4]=t1.x;A[5]=t1.y;A[6]=t1.z;A[7]=t1.w;
      A[8]=t2.x;A[9]=t2.y;A[10]=t2.z;A[11]=t2.w; A[12]=t3.x;A[13]=t3.y;A[14]=t3.z;A[15]=t3.w;
      A[16]=t4.x;A[17]=t4.y;A[18]=t4.z;A[19]=t4.w; A[20]=t5.x;A[21]=t5.y;A[22]=t5.z;A[23]=t5.w;
      A[24]=t6.x;A[25]=t6.y;A[26]=t6.z;A[27]=t6.w; A[28]=t7.x;A[29]=t7.y;
    }
    const float* W1u=W1+hfu*15;
    const float* b1u=b1+hfu*15;
    #pragma unroll
    for (int jo=0;jo<15;jo++) h[jo]=b1u[jo];
    #pragma unroll
    for (int i=0;i<FIN;i++){
      float ai=A[i];
      #pragma unroll
      for (int jo=0;jo<15;jo++) h[jo]=fmaf(ai,W1u[i*H1+jo],h[jo]);
    }
    #pragma unroll
    for (int jo=0;jo<15;jo++) h[jo]=fmaxf(h[jo],0.f);
  }

  // ---- pool1 partial score (per half) -> sd ----
  {
    const float* p1u=p1+hfu*15;
    float d=0.f;
    #pragma unroll
    for (int jo=0;jo<15;jo++) d += h[jo]*p1u[jo];
    AGG[SD0 + hf*128 + nG]=d;
  }
  __syncthreads();
  if (tid<NN){
    float nr=0.f;
    #pragma unroll
    for (int i=0;i<H1;i++){ float pv=p1[i]; nr+=pv*pv; }
    float dtot=AGG[SD0+tid]+AGG[SD0+128+tid];
    dsc[tid]=tanhf(dtot/sqrtf(nr));
  }
  __syncthreads();
  {  // stable rank (pair-split, tid-mapped)
    int nR=tid>>1, hR=tid&1;
    float si=dsc[nR];
    int m0=hR<<6, r=0;
    for (int m=m0;m<m0+64;m++){ float sm=dsc[m]; r += (sm>si)||(sm==si&&m<nR); }
    r += __shfl_xor(r,1,64);
    if (!hR) rmap[nR]=(r<K1)?(signed char)r:(signed char)-1;
  }
  __syncthreads();
  {  // gated compact -> swizzled XB rows by rank (wave-mapped, h in regs)
    int r=rmap[nG];
    if (r>=0){
      float gv=dsc[nG];
      #pragma unroll
      for (int j=0;j<15;j++){
        int i=hfu*15+j;
        XB[(r<<5)+((((i>>2)+r)&7)<<2)+(i&3)]=h[j]*gv;
      }
    }
  }
  #pragma unroll
  for (int j=0;j<EPT;j++){
    int ns=rmap[epk[j]&255], nd=rmap[epk[j]>>8];
    epk[j]=((ns|nd)<0)? -1 : (ns|(nd<<8));
  }
  if (tid<K1) cur[tid]=0;
  __syncthreads();

  // ================= CSR build 2 =================
  #pragma unroll
  for (int j=0;j<EPT;j++) if (epk[j]>=0) atomicAdd(&cur[epk[j]>>8],1);
  __syncthreads();
  {
    int mydeg=(tid<K1)?cur[tid]:0;
    int mydeg4=(mydeg+3)&~3;
    int v=mydeg4;
    #pragma unroll
    for (int off=1;off<64;off<<=1){ int t=__shfl_up(v,off,64); if (lane>=off) v+=t; }
    if (tid==63) sh_wtot=v;
    for (int l=tid;l<EGP/4;l+=NT) ((int*)eord)[l]=-1;
    __syncthreads();
    int start=v-mydeg4+((tid>=64)?sh_wtot:0);
    if (tid<K1){ cur[tid]=start; cstart[tid]=(short)start; dsc[tid]=1.0f/sqrtf((float)mydeg+1.0f); }
  }
  __syncthreads();
  #pragma unroll
  for (int j=0;j<EPT;j++) if (epk[j]>=0){ int p=atomicAdd(&cur[epk[j]>>8],1); eord[p]=(unsigned char)(epk[j]&255); }
  __syncthreads();

  // ================= gather2 (wave-mapped, nG<K1) ============================
  if (nG<K1){
    float4 ac0={0,0,0,0},ac1={0,0,0,0},ac2={0,0,0,0},ac3={0,0,0,0};
    const int cq=hf<<2;
    int e0=cstart[nG], deg=cur[nG]-e0;
    float di=dsc[nG];
    int kend=e0+((deg+3)&~3);
    for (int k=e0;k<kend;k+=4){
      uchar4 ss=*(const uchar4*)&eord[k];
      float w0=(ss.x<128)? di*dsc[ss.x&127] : 0.f;
      float w1=(ss.y<128)? di*dsc[ss.y&127] : 0.f;
      float w2=(ss.z<128)? di*dsc[ss.z&127] : 0.f;
      float w3=(ss.w<128)? di*dsc[ss.w&127] : 0.f;
      row_fma(ss.x&127,w0,XB,cq,ac0,ac1,ac2,ac3);
      row_fma(ss.y&127,w1,XB,cq,ac0,ac1,ac2,ac3);
      row_fma(ss.z&127,w2,XB,cq,ac0,ac1,ac2,ac3);
      row_fma(ss.w&127,w3,XB,cq,ac0,ac1,ac2,ac3);
    }
    row_fma(nG, 1.0f/((float)deg+1.0f), XB, cq, ac0,ac1,ac2,ac3);
    float* dp=&AGG[nG*SA + (hf<<4)];
    ((float4*)dp)[0]=ac0; ((float4*)dp)[1]=ac1; ((float4*)dp)[2]=ac2;
    if (!hf) ((float4*)dp)[3]=ac3;
    else     *(float2*)(dp+12)=make_float2(ac3.x,ac3.y);
  }
  __syncthreads();                 // h1g dead; agg2 ready

  // ================= mm2: scalar-W + pool2 partial ===========================
  float oc[25];
  if (nG<K1){
    float A[30];
    {
      const float* arow=&AGG[nG*SA];
      float4 t0=((const float4*)arow)[0],t1=((const float4*)arow)[1],t2=((const float4*)arow)[2],
             t3=((const float4*)arow)[3],t4=((const float4*)arow)[4],t5=((const float4*)arow)[5],
             t6=((const float4*)arow)[6];
      float2 t7=*(const float2*)(arow+28);
      A[0]=t0.x;A[1]=t0.y;A[2]=t0.z;A[3]=t0.w; A[4]=t1.x;A[5]=t1.y;A[6]=t1.z;A[7]=t1.w;
      A[8]=t2.x;A[9]=t2.y;A[10]=t2.z;A[11]=t2.w; A[12]=t3.x;A[13]=t3.y;A[14]=t3.z;A[15]=t3.w;
      A[16]=t4.x;A[17]=t4.y;A[18]=t4.z;A[19]=t4.w; A[20]=t5.x;A[21]=t5.y;A[22]=t5.z;A[23]=t5.w;
      A[24]=t6.x;A[25]=t6.y;A[26]=t6.z;A[27]=t6.w; A[28]=t7.x;A[29]=t7.y;
    }
    const float* W2u=W2+hfu*25;
    const float* b2u=b2+hfu*25;
    #pragma unroll
    for (int jo=0;jo<25;jo++) oc[jo]=b2u[jo];
    #pragma unroll
    for (int i=0;i<H1;i++){
      float ai=A[i];
      #pragma unroll
      for (int jo=0;jo<25;jo++) oc[jo]=fmaf(ai,W2u[i*H2+jo],oc[jo]);
    }
    const float* p2u=p2+hfu*25;
    float d=0.f;
    #pragma unroll
    for (int jo=0;jo<25;jo++){ oc[jo]=fmaxf(oc[jo],0.f); d += oc[jo]*p2u[jo]; }
    AGG[SD0 + hf*128 + nG]=d;
  }
  __syncthreads();
  if (tid<K1){
    float nr=0.f;
    #pragma unroll
    for (int i=0;i<H2;i++){ float pv=p2[i]; nr+=pv*pv; }
    float dtot=AGG[SD0+tid]+AGG[SD0+128+tid];
    dsc[tid]=tanhf(dtot/sqrtf(nr));
  }
  __syncthreads();
  {  // rank2 (pair-split, keep flag)
    int nR=tid>>1, hR=tid&1;
    float si=(nR<K1)?dsc[nR]:0.f;
    int m0=hR?52:0, m1=hR?K1:52, r=0;
    for (int m=m0;m<m1;m++){ float sm=dsc[m]; r += (sm>si)||(sm==si&&m<nR); }
    r += __shfl_xor(r,1,64);
    if (!hR && nR<K1) rmap[nR]=(r<K2)?(signed char)1:(signed char)-1;
  }
  __syncthreads();

  // ================= gated global max/mean ===================================
  {
    bool kept=(nG<K1)&&(rmap[nG]>0);
    float gv=kept?dsc[nG]:0.f;
    float mx[25],sm[25];
    #pragma unroll
    for (int j=0;j<25;j++){ float v=oc[j]*gv; sm[j]=kept?v:0.f; mx[j]=kept?v:-3.4e38f; }
    #pragma unroll
    for (int off=1;off<64;off<<=1){
      #pragma unroll
      for (int j=0;j<25;j++){ mx[j]=fmaxf(mx[j],__shfl_xor(mx[j],off,64)); sm[j]+=__shfl_xor(sm[j],off,64); }
    }
    if (lane==0){
      #pragma unroll
      for (int j=0;j<25;j++){ AGG[PMX+wv*25+j]=mx[j]; AGG[PSM+wv*25+j]=sm[j]; }
    }
  }
  __syncthreads();
  if (tid<H2){
    int hfX=(tid>=25), j=tid-hfX*25;
    float m=fmaxf(AGG[PMX+hfX*25+j], AGG[PMX+(hfX+2)*25+j]);
    float s=AGG[PSM+hfX*25+j]+AGG[PSM+(hfX+2)*25+j];
    AGG[POL+tid]=m;
    AGG[POL+H2+tid]=s*(1.0f/(float)K2);
  }
  __syncthreads();

  // ================= fc1 + fc2 =================
  if (tid<FCW){
    float acc=fc1b[tid];
    #pragma unroll 4
    for (int i=0;i<2*H2;i++) acc += AGG[POL+i]*fc1W[i*FCW+tid];
    AGG[ZFC+tid]=fmaxf(acc,0.f);
  }
  __syncthreads();
  if (tid<64){
    float a=0.f;
    for (int j=tid;j<FCW;j+=64) a += AGG[ZFC+j]*fc2W[j];
    #pragma unroll
    for (int off=32;off;off>>=1) a += __shfl_down(a,off,64);
    if (tid==0){
      float acc=fc2b[0]+a;
      out[g]=1.0f/(1.0f+expf(-acc));
    }
  }
}

extern "C" void kernel_launch(void* const* d_in, const int* in_sizes, int n_in,
                              void* d_out, int out_size, void* d_ws, size_t ws_size,
                              hipStream_t stream) {
  const float* x    = (const float*)d_in[0];
  const int*   ei   = (const int*)d_in[1];
  // d_in[2] = batch (unused; graphs are equal-size, contiguous)
  const float* W1   = (const float*)d_in[3];
  const float* b1   = (const float*)d_in[4];
  const float* p1   = (const float*)d_in[5];
  const float* W2   = (const float*)d_in[6];
  const float* b2   = (const float*)d_in[7];
  const float* p2   = (const float*)d_in[8];
  const float* fc1W = (const float*)d_in[9];
  const float* fc1b = (const float*)d_in[10];
  const float* fc2W = (const float*)d_in[11];
  const float* fc2b = (const float*)d_in[12];
  float* outp = (float*)d_out;

  gnn_fused<<<BGR, NT, 0, stream>>>(x, ei, W1, b1, p1, W2, b2, p2,
                                    fc1W, fc1b, fc2W, fc2b, outp);
}